// Round 1
// 248.392 us; speedup vs baseline: 1.0008x; 1.0008x over previous
//
#include <hip/hip_runtime.h>
#include <math.h>
#include <limits.h>

#define NPIX (512*512)
#define NB 16
#define RAD 60
#define DSZ 120
#define PSTR 121   // padded LDS stride for patch kernel

// fused warp-chain LDS region caps (odd strides -> no bank conflicts)
#define C1 48      // pred_rot region cap
#define SR_S 49
#define C2 62      // pred_trans region cap
#define ST_S 63
#define C3 66      // base_inp region cap
#define SB_S 67

// ---------------- device helpers ----------------

// torch/jax grid_sample semantics: bilinear, zero padding, align_corners=False
__device__ __forceinline__ float gs_bilinear(const float* img, int H, int W,
                                             float gx, float gy) {
    float x = ((gx + 1.0f) * (float)W - 1.0f) * 0.5f;
    float y = ((gy + 1.0f) * (float)H - 1.0f) * 0.5f;
    float xf = floorf(x), yf = floorf(y);
    int ix = (int)xf, iy = (int)yf;
    float wx = x - xf, wy = y - yf;
    float v = 0.0f;
    bool vx0 = (ix >= 0) && (ix < W);
    bool vx1 = (ix >= -1) && (ix < W - 1);
    bool vy0 = (iy >= 0) && (iy < H);
    bool vy1 = (iy >= -1) && (iy < H - 1);
    if (vx0 && vy0) v += img[iy*W + ix]         * ((1.0f - wx) * (1.0f - wy));
    if (vx1 && vy0) v += img[iy*W + ix + 1]     * (wx * (1.0f - wy));
    if (vx0 && vy1) v += img[(iy+1)*W + ix]     * ((1.0f - wx) * wy);
    if (vx1 && vy1) v += img[(iy+1)*W + ix + 1] * (wx * wy);
    return v;
}

// LDS patch with padded row stride PSTR, logical 120x120
__device__ __forceinline__ float gs_bilinear_patch(const float* img, float gx, float gy) {
    float x = ((gx + 1.0f) * 120.0f - 1.0f) * 0.5f;
    float y = ((gy + 1.0f) * 120.0f - 1.0f) * 0.5f;
    float xf = floorf(x), yf = floorf(y);
    int ix = (int)xf, iy = (int)yf;
    float wx = x - xf, wy = y - yf;
    float v = 0.0f;
    bool vx0 = (ix >= 0) && (ix < 120);
    bool vx1 = (ix >= -1) && (ix < 119);
    bool vy0 = (iy >= 0) && (iy < 120);
    bool vy1 = (iy >= -1) && (iy < 119);
    if (vx0 && vy0) v += img[iy*PSTR + ix]         * ((1.0f - wx) * (1.0f - wy));
    if (vx1 && vy0) v += img[iy*PSTR + ix + 1]     * (wx * (1.0f - wy));
    if (vx0 && vy1) v += img[(iy+1)*PSTR + ix]     * ((1.0f - wx) * wy);
    if (vx1 && vy1) v += img[(iy+1)*PSTR + ix + 1] * (wx * wy);
    return v;
}

// jax.image.resize linear 128->512 at one output pixel (identical arithmetic to old k_init)
__device__ __forceinline__ float upsample_val(const float* __restrict__ src, int y, int x) {
    float sy = (float)y * 0.25f - 0.375f;
    float fy0 = floorf(sy);
    int iy = (int)fy0;
    float fy = sy - fy0;
    int iy0 = min(max(iy, 0), 127), iy1 = min(max(iy + 1, 0), 127);
    float sx = (float)x * 0.25f - 0.375f;
    float fx0 = floorf(sx);
    int ix = (int)fx0;
    float fx = sx - fx0;
    int ix0 = min(max(ix, 0), 127), ix1 = min(max(ix + 1, 0), 127);
    float v00 = src[iy0 * 128 + ix0], v10 = src[iy0 * 128 + ix1];
    float v01 = src[iy1 * 128 + ix0], v11 = src[iy1 * 128 + ix1];
    return (v00 * (1.0f - fx) + v10 * fx) * (1.0f - fy)
         + (v01 * (1.0f - fx) + v11 * fx) * fy;
}

// map integer pixel (x,y) through affine theta to source sample coords (512x512 space)
__device__ __forceinline__ void smap512(const float* th, float x, float y,
                                        float& sx, float& sy) {
    float X = (2.0f * x + 1.0f) / 512.0f - 1.0f;
    float Y = (2.0f * y + 1.0f) / 512.0f - 1.0f;
    float gx = th[0] * X + th[1] * Y + th[2];
    float gy = th[3] * X + th[4] * Y + th[5];
    sx = ((gx + 1.0f) * 512.0f - 1.0f) * 0.5f;
    sy = ((gy + 1.0f) * 512.0f - 1.0f) * 0.5f;
}

// conservative source-pixel bbox of rect [x0,x1]x[y0,y1] mapped through theta
__device__ __forceinline__ void corner_bbox(const float* th, float x0, float x1,
                                            float y0, float y1,
                                            int& lx, int& ly, int& w, int& h) {
    float sxmin = 1e30f, sxmax = -1e30f, symin = 1e30f, symax = -1e30f;
    #pragma unroll
    for (int cy = 0; cy < 2; ++cy)
        #pragma unroll
        for (int cx = 0; cx < 2; ++cx) {
            float sx, sy;
            smap512(th, cx ? x1 : x0, cy ? y1 : y0, sx, sy);
            sxmin = fminf(sxmin, sx); sxmax = fmaxf(sxmax, sx);
            symin = fminf(symin, sy); symax = fmaxf(symax, sy);
        }
    lx = (int)floorf(sxmin) - 1;
    ly = (int)floorf(symin) - 1;
    w  = (int)floorf(sxmax) + 2 - lx + 1;
    h  = (int)floorf(symax) + 2 - ly + 1;
}

// ---- exact slow-path chain (rarely taken; only if LDS caps exceeded) ----
__device__ __forceinline__ float fb_binp(const float* bs, int x, int y) {
    if (x < 0 || x >= 512 || y < 0 || y >= 512) return 0.0f;
    return upsample_val(bs, y, x);
}
__device__ __forceinline__ float fb_trans(const float* bs, const float* th3, int x, int y) {
    if (x < 0 || x >= 512 || y < 0 || y >= 512) return 0.0f;
    float sx, sy; smap512(th3, (float)x, (float)y, sx, sy);
    float xf = floorf(sx), yf = floorf(sy);
    int ix = (int)xf, iy = (int)yf;
    float wx = sx - xf, wy = sy - yf;
    return fb_binp(bs, ix, iy)         * ((1.0f - wx) * (1.0f - wy))
         + fb_binp(bs, ix + 1, iy)     * (wx * (1.0f - wy))
         + fb_binp(bs, ix, iy + 1)     * ((1.0f - wx) * wy)
         + fb_binp(bs, ix + 1, iy + 1) * (wx * wy);
}
__device__ __forceinline__ float fb_rot(const float* bs, const float* th2,
                                        const float* th3, int x, int y) {
    if (x < 0 || x >= 512 || y < 0 || y >= 512) return 0.0f;
    float sx, sy; smap512(th2, (float)x, (float)y, sx, sy);
    float xf = floorf(sx), yf = floorf(sy);
    int ix = (int)xf, iy = (int)yf;
    float wx = sx - xf, wy = sy - yf;
    return fb_trans(bs, th3, ix, iy)         * ((1.0f - wx) * (1.0f - wy))
         + fb_trans(bs, th3, ix + 1, iy)     * (wx * (1.0f - wy))
         + fb_trans(bs, th3, ix, iy + 1)     * ((1.0f - wx) * wy)
         + fb_trans(bs, th3, ix + 1, iy + 1) * (wx * wy);
}

// ---------------- stage 1: occ + prep (small) ----------------
__global__ void __launch_bounds__(256) k_pre(const float* __restrict__ sc,
                                             const float* __restrict__ rot,
                                             const float* __restrict__ tr,
                                             const float* __restrict__ masks,
                                             float* __restrict__ ws_inv,
                                             int* __restrict__ bbox,
                                             unsigned* __restrict__ occ,
                                             int* __restrict__ qcount) {
    int bid = blockIdx.x;
    if (bid < 32) {
        // ---- occ: one wave computes one occ word (tile-row of one mask) ----
        int word = bid * 4 + (threadIdx.x >> 6);            // 0..127
        int lane = threadIdx.x & 63;
        int j = word >> 5, ty = word & 31;
        const float* mk = masks + (size_t)j * NPIX + ty * 16 * 512 + lane * 8;
        int any = 0;
        for (int rr = 0; rr < 16; ++rr) {
            const float4* p = (const float4*)(mk + rr * 512);
            float4 a = p[0], c = p[1];
            if (a.x != 0.f || a.y != 0.f || a.z != 0.f || a.w != 0.f ||
                c.x != 0.f || c.y != 0.f || c.z != 0.f || c.w != 0.f) any = 1;
        }
        unsigned long long bb = __ballot(any);
        if (lane == 0) {
            unsigned wrd = 0;
            for (int tx = 0; tx < 32; ++tx)
                if (bb & (3ull << (2 * tx))) wrd |= 1u << tx;
            occ[j * 32 + ty] = wrd;
        }
    } else {
        // ---- prep: theta inverses + bbox/qcount init ----
        int t = threadIdx.x;
        if (t < 48) {
            int m = t >> 4, b = t & 15;
            const float* th = (m == 0 ? sc : (m == 1 ? rot : tr)) + b * 6;
            float a  = th[0], bbv = th[1], tx = th[2];
            float c  = th[3], d   = th[4], ty = th[5];
            float L10 = c / a;
            float dp  = d  - L10 * bbv;
            float typ = ty - L10 * tx;
            float i10 = (0.0f - L10) / dp;
            float i00 = (1.0f - bbv * i10) / a;
            float i11 = 1.0f / dp;
            float i01 = (0.0f - bbv * i11) / a;
            float i12 = (0.0f - typ) / dp;
            float i02 = (0.0f - bbv * i12 - tx) / a;
            float* o = ws_inv + m * 96 + b * 6;
            o[0] = i00; o[1] = i01; o[2] = i02;
            o[3] = i10; o[4] = i11; o[5] = i12;
        }
        bbox[t] = ((t & 3) < 2) ? INT_MAX : INT_MIN;
        if (t == 0) *qcount = 0;
    }
}

// ---------------- stage 2: fused upsample + g3 + g2 + g1 + otile ----------------
// blocks [0,4096): one 32x32 output tile, full warp chain in LDS
// blocks [4096,4352): otile classification (live tiles -> queue + byte map)
__global__ void __launch_bounds__(256) k_main(const float* __restrict__ base,
                                              float* __restrict__ out0,
                                              float* __restrict__ out1,
                                              float* __restrict__ out2,
                                              const float* __restrict__ inv1,
                                              const float* __restrict__ inv2,
                                              const float* __restrict__ inv3,
                                              const unsigned* __restrict__ occ,
                                              unsigned char* __restrict__ otile,
                                              int* __restrict__ queue,
                                              int* __restrict__ qcount) {
    __shared__ float sb[C3 * SB_S];   // base_inp region
    __shared__ float st[C2 * ST_S];   // pred_trans region
    __shared__ float sr[C1 * SR_S];   // pred_rot region
    int bid = blockIdx.x;

    if (bid >= 4096) {
        // ---- otile classification (unchanged math) ----
        int idx = (bid - 4096) * 256 + threadIdx.x;   // 0..65535
        int jb = idx >> 10, tile = idx & 1023;
        int j = jb >> 4, bb_ = jb & 15;
        int ty = tile >> 5, tx = tile & 31;
        const float* t1 = inv1 + bb_ * 6;
        const float* t2 = inv2 + bb_ * 6;
        float xs[2] = { (float)(tx * 16), (float)(tx * 16 + 15) };
        float ys[2] = { (float)(ty * 16), (float)(ty * 16 + 15) };
        float sxmin = 1e30f, sxmax = -1e30f, symin = 1e30f, symax = -1e30f;
        for (int cy = 0; cy < 2; ++cy)
            for (int cx = 0; cx < 2; ++cx) {
                float sx, sy;
                smap512(t1, xs[cx], ys[cy], sx, sy);
                sxmin = fminf(sxmin, sx); sxmax = fmaxf(sxmax, sx);
                symin = fminf(symin, sy); symax = fmaxf(symax, sy);
            }
        int c0 = max((int)floorf(sxmin) - 1, 0), c1 = min((int)floorf(sxmax) + 2, 511);
        int r0 = max((int)floorf(symin) - 1, 0), r1 = min((int)floorf(symax) + 2, 511);
        bool any = false;
        if (c0 <= c1 && r0 <= r1) {
            float A0 = t2[0], A1 = t2[1], A3 = t2[3], A4 = t2[4];
            float Kx = 0.5f * (-511.0f * (A0 + A1) + 512.0f * t2[2] + 511.0f);
            float Ky = 0.5f * (-511.0f * (A3 + A4) + 512.0f * t2[5] + 511.0f);
            float pxmin = A0 * (A0 >= 0.f ? c0 : c1) + A1 * (A1 >= 0.f ? r0 : r1) + Kx;
            float pxmax = A0 * (A0 >= 0.f ? c1 : c0) + A1 * (A1 >= 0.f ? r1 : r0) + Kx;
            float pymin = A3 * (A3 >= 0.f ? c0 : c1) + A4 * (A4 >= 0.f ? r0 : r1) + Ky;
            float pymax = A3 * (A3 >= 0.f ? c1 : c0) + A4 * (A4 >= 0.f ? r1 : r0) + Ky;
            int xlo = max((int)floorf(pxmin) - 1, 0), xhi = min((int)floorf(pxmax) + 2, 511);
            int ylo = max((int)floorf(pymin) - 1, 0), yhi = min((int)floorf(pymax) + 2, 511);
            if (xlo <= xhi && ylo <= yhi)
                for (int tr_ = ylo >> 4; tr_ <= yhi >> 4; ++tr_)
                    for (int tc = xlo >> 4; tc <= xhi >> 4; ++tc)
                        if ((occ[j * 32 + tr_] >> tc) & 1u) any = true;
        }
        otile[idx] = any ? 1 : 0;
        if (any) {
            int pos = atomicAdd(qcount, 1);
            queue[pos] = (jb << 10) | tile;
        }
        return;
    }

    // ---- warp-chain tile ----
    int b = bid >> 8, tile = bid & 255;
    int ox = (tile & 15) * 32, oy = (tile >> 4) * 32;
    const float* bsrc = base + b * 128 * 128;
    float a1[6], a2[6], a3[6];
    #pragma unroll
    for (int k = 0; k < 6; ++k) {
        a1[k] = inv1[b * 6 + k];
        a2[k] = inv2[b * 6 + k];
        a3[k] = inv3[b * 6 + k];
    }
    int t = threadIdx.x;
    int py = oy + (t >> 3);
    int px0 = ox + (t & 7) * 4;

    // out0 (base_inp) tile — identical values to the old k_init upsample
    {
        float4 v4 = make_float4(upsample_val(bsrc, py, px0),
                                upsample_val(bsrc, py, px0 + 1),
                                upsample_val(bsrc, py, px0 + 2),
                                upsample_val(bsrc, py, px0 + 3));
        *(float4*)(out0 + (size_t)b * NPIX + py * 512 + px0) = v4;
    }

    // dependency-cone bboxes: out tile -> pred_rot (R1) -> pred_trans (R2) -> base_inp (R3)
    int lx1, ly1, w1, h1;
    corner_bbox(a1, (float)ox, (float)(ox + 31), (float)oy, (float)(oy + 31),
                lx1, ly1, w1, h1);
    int lx2, ly2, w2, h2;
    corner_bbox(a2, (float)lx1, (float)(lx1 + w1 - 1), (float)ly1, (float)(ly1 + h1 - 1),
                lx2, ly2, w2, h2);
    int lx3, ly3, w3, h3;
    corner_bbox(a3, (float)lx2, (float)(lx2 + w2 - 1), (float)ly2, (float)(ly2 + h2 - 1),
                lx3, ly3, w3, h3);
    bool fits = (w1 <= C1) && (h1 <= C1) && (w2 <= C2) && (h2 <= C2) &&
                (w3 <= C3) && (h3 <= C3);

    float r[4];
    if (fits) {
        // stage B: base_inp region (0 outside image = zero padding)
        for (int i = t; i < w3 * h3; i += 256) {
            int rr = i / w3, cc = i - rr * w3;
            int gy = ly3 + rr, gx = lx3 + cc;
            float v = 0.0f;
            if (gx >= 0 && gx < 512 && gy >= 0 && gy < 512)
                v = upsample_val(bsrc, gy, gx);
            sb[rr * SB_S + cc] = v;
        }
        __syncthreads();
        // stage C: pred_trans region = g3-sample of base_inp
        for (int i = t; i < w2 * h2; i += 256) {
            int rr = i / w2, cc = i - rr * w2;
            int gy = ly2 + rr, gx = lx2 + cc;
            float v = 0.0f;
            if (gx >= 0 && gx < 512 && gy >= 0 && gy < 512) {
                float sx, sy; smap512(a3, (float)gx, (float)gy, sx, sy);
                float xf = floorf(sx), yf = floorf(sy);
                int ix = (int)xf - lx3, iy = (int)yf - ly3;
                float wx = sx - xf, wy = sy - yf;
                v  = sb[iy * SB_S + ix]           * ((1.0f - wx) * (1.0f - wy));
                v += sb[iy * SB_S + ix + 1]       * (wx * (1.0f - wy));
                v += sb[(iy + 1) * SB_S + ix]     * ((1.0f - wx) * wy);
                v += sb[(iy + 1) * SB_S + ix + 1] * (wx * wy);
            }
            st[rr * ST_S + cc] = v;
        }
        __syncthreads();
        // stage D: pred_rot region = g2-sample of pred_trans
        for (int i = t; i < w1 * h1; i += 256) {
            int rr = i / w1, cc = i - rr * w1;
            int gy = ly1 + rr, gx = lx1 + cc;
            float v = 0.0f;
            if (gx >= 0 && gx < 512 && gy >= 0 && gy < 512) {
                float sx, sy; smap512(a2, (float)gx, (float)gy, sx, sy);
                float xf = floorf(sx), yf = floorf(sy);
                int ix = (int)xf - lx2, iy = (int)yf - ly2;
                float wx = sx - xf, wy = sy - yf;
                v  = st[iy * ST_S + ix]           * ((1.0f - wx) * (1.0f - wy));
                v += st[iy * ST_S + ix + 1]       * (wx * (1.0f - wy));
                v += st[(iy + 1) * ST_S + ix]     * ((1.0f - wx) * wy);
                v += st[(iy + 1) * ST_S + ix + 1] * (wx * wy);
            }
            sr[rr * SR_S + cc] = v;
        }
        __syncthreads();
        // stage E: pred_input = g1-sample of pred_rot
        #pragma unroll
        for (int k = 0; k < 4; ++k) {
            float sx, sy; smap512(a1, (float)(px0 + k), (float)py, sx, sy);
            float xf = floorf(sx), yf = floorf(sy);
            int ix = (int)xf - lx1, iy = (int)yf - ly1;
            float wx = sx - xf, wy = sy - yf;
            float v;
            v  = sr[iy * SR_S + ix]           * ((1.0f - wx) * (1.0f - wy));
            v += sr[iy * SR_S + ix + 1]       * (wx * (1.0f - wy));
            v += sr[(iy + 1) * SR_S + ix]     * ((1.0f - wx) * wy);
            v += sr[(iy + 1) * SR_S + ix + 1] * (wx * wy);
            r[k] = v;
        }
    } else {
        // exact fallback: fully nested per-pixel chain (block-uniform branch)
        #pragma unroll
        for (int k = 0; k < 4; ++k) {
            float sx, sy; smap512(a1, (float)(px0 + k), (float)py, sx, sy);
            float xf = floorf(sx), yf = floorf(sy);
            int ix = (int)xf, iy = (int)yf;
            float wx = sx - xf, wy = sy - yf;
            r[k] = fb_rot(bsrc, a2, a3, ix, iy)         * ((1.0f - wx) * (1.0f - wy))
                 + fb_rot(bsrc, a2, a3, ix + 1, iy)     * (wx * (1.0f - wy))
                 + fb_rot(bsrc, a2, a3, ix, iy + 1)     * ((1.0f - wx) * wy)
                 + fb_rot(bsrc, a2, a3, ix + 1, iy + 1) * (wx * wy);
        }
    }
    float4 v4 = make_float4(r[0], r[1], r[2], r[3]);
    size_t op = (size_t)b * NPIX + py * 512 + px0;
    *(float4*)(out1 + op) = v4;
    *(float4*)(out2 + op) = v4;
}

__device__ __forceinline__ float rm2_val(const float* mk, const float* t2, int cx_, int ry_) {
    float X2 = (2.0f * (float)cx_ + 1.0f) / 512.0f - 1.0f;
    float Y2 = (2.0f * (float)ry_ + 1.0f) / 512.0f - 1.0f;
    float g2x = t2[0] * X2 + t2[1] * Y2 + t2[2];
    float g2y = t2[3] * X2 + t2[4] * Y2 + t2[5];
    return gs_bilinear(mk, 512, 512, g2x, g2y);
}

// stage 3: masked zero-fill of dead tiles + mask chain on live tiles (disjoint writes)
// blocks [0,2048): zero dead float4s; [2048,3072): queue consumer
__global__ void __launch_bounds__(256) k_zml(const float* __restrict__ masks,
                                             float* __restrict__ out3,
                                             const float* __restrict__ inv1,
                                             const float* __restrict__ inv2,
                                             const unsigned char* __restrict__ otile,
                                             const int* __restrict__ queue,
                                             const int* __restrict__ qcount,
                                             int* __restrict__ bbox) {
    int bid = blockIdx.x;
    if (bid < 2048) {
        const float4 z4 = make_float4(0.f, 0.f, 0.f, 0.f);
        float4* p = (float4*)out3;
        int stride = 2048 * 256;
        for (int i = bid * 256 + threadIdx.x; i < 64 * NPIX / 4; i += stride) {
            int jb = i >> 16;             // 65536 float4 per (j,b) image
            int w = i & 65535;
            int y = w >> 7;               // (w*4)>>9
            int x = (w << 2) & 511;
            int tile = ((y >> 4) << 5) | (x >> 4);   // float4 never spans tiles (4|x)
            if (!otile[(jb << 10) | tile]) p[i] = z4;
        }
        return;
    }
    __shared__ int sbb[4];
    int n = *qcount;
    for (int q = bid - 2048; q < n; q += 1024) {
        int e = queue[q];
        int jb = e >> 10, tile = e & 1023;
        if (threadIdx.x == 0) { sbb[0] = INT_MAX; sbb[1] = INT_MAX; sbb[2] = INT_MIN; sbb[3] = INT_MIN; }
        __syncthreads();

        int ty = tile >> 5, tx = tile & 31;
        int y = ty * 16 + (threadIdx.x >> 4);
        int x = tx * 16 + (threadIdx.x & 15);
        int j = jb >> 4, b = jb & 15;
        const float* t1 = inv1 + b * 6;
        const float* t2 = inv2 + b * 6;
        const float* mk = masks + (size_t)j * NPIX;

        float X = (2.0f * (float)x + 1.0f) / 512.0f - 1.0f;
        float Y = (2.0f * (float)y + 1.0f) / 512.0f - 1.0f;
        float gx = t1[0] * X + t1[1] * Y + t1[2];
        float gy = t1[3] * X + t1[4] * Y + t1[5];
        float sx = ((gx + 1.0f) * 512.0f - 1.0f) * 0.5f;
        float sy = ((gy + 1.0f) * 512.0f - 1.0f) * 0.5f;
        float xf = floorf(sx), yf = floorf(sy);
        int ix = (int)xf, iy = (int)yf;
        float wx = sx - xf, wy = sy - yf;

        float v = 0.0f;
        bool vx0 = (ix >= 0) && (ix < 512);
        bool vx1 = (ix >= -1) && (ix < 511);
        bool vy0 = (iy >= 0) && (iy < 512);
        bool vy1 = (iy >= -1) && (iy < 511);
        if (vx0 && vy0) v += rm2_val(mk, t2, ix,     iy    ) * ((1.0f - wx) * (1.0f - wy));
        if (vx1 && vy0) v += rm2_val(mk, t2, ix + 1, iy    ) * (wx * (1.0f - wy));
        if (vx0 && vy1) v += rm2_val(mk, t2, ix,     iy + 1) * ((1.0f - wx) * wy);
        if (vx1 && vy1) v += rm2_val(mk, t2, ix + 1, iy + 1) * (wx * wy);

        float res = 0.0f;
        if (v >= 0.5f) {
            res = 1.0f;
            atomicMin(&sbb[0], y); atomicMin(&sbb[1], x);
            atomicMax(&sbb[2], y); atomicMax(&sbb[3], x);
        }
        out3[(size_t)jb * NPIX + y * 512 + x] = res;

        __syncthreads();
        if (threadIdx.x == 0 && sbb[2] != INT_MIN) {
            atomicMin(&bbox[jb * 4 + 0], sbb[0]);
            atomicMin(&bbox[jb * 4 + 1], sbb[1]);
            atomicMax(&bbox[jb * 4 + 2], sbb[2]);
            atomicMax(&bbox[jb * 4 + 3], sbb[3]);
        }
        __syncthreads();
    }
}

// stage 4: fused COM stats -> crop origins
__global__ void __launch_bounds__(256) k_stats(const float* __restrict__ pred,
                                               const float* __restrict__ mrot,
                                               const int* __restrict__ bbox,
                                               int* __restrict__ xy) {
    int jb = blockIdx.x;
    int b = jb & 15;
    int rmin = bbox[jb*4+0], cmin = bbox[jb*4+1], rmax = bbox[jb*4+2], cmax = bbox[jb*4+3];
    const float* img = pred + (size_t)b * NPIX;
    const float* mk  = mrot + (size_t)jb * NPIX;
    int lane = threadIdx.x & 63, w = threadIdx.x >> 6;
    int W = cmax - cmin + 1;
    int total = (rmax >= rmin) ? W * (rmax - rmin + 1) : 0;

    double msum = 0.0, isum = 0.0;
    for (int i = threadIdx.x; i < total; i += 256) {
        int r = rmin + i / W, c = cmin + i % W;
        float m = mk[r * 512 + c];
        if (m != 0.0f) {
            msum += (double)m;
            isum += (double)(img[r * 512 + c] * m);
        }
    }
    for (int o = 32; o > 0; o >>= 1) {
        msum += __shfl_down(msum, o, 64);
        isum += __shfl_down(isum, o, 64);
    }
    __shared__ double s0[4], s1[4], s2[4];
    __shared__ double sthr;
    if (lane == 0) { s0[w] = msum; s1[w] = isum; }
    __syncthreads();
    if (threadIdx.x == 0) {
        double M = s0[0] + s0[1] + s0[2] + s0[3];
        double I = s1[0] + s1[1] + s1[2] + s1[3];
        sthr = (I / fmax(M, 1.0)) * 1.5;
    }
    __syncthreads();
    double t = sthr;

    double wsum = 0.0, sy = 0.0, sx = 0.0;
    for (int i = threadIdx.x; i < total; i += 256) {
        int r = rmin + i / W, c = cmin + i % W;
        float m = mk[r * 512 + c];
        if (m != 0.0f) {
            float v = img[r * 512 + c] * m;
            if ((double)v > t) {
                double vd = (double)v;
                wsum += vd;
                sy += vd * (double)r;
                sx += vd * (double)c;
            }
        }
    }
    for (int o = 32; o > 0; o >>= 1) {
        wsum += __shfl_down(wsum, o, 64);
        sy   += __shfl_down(sy,   o, 64);
        sx   += __shfl_down(sx,   o, 64);
    }
    __syncthreads();
    if (lane == 0) { s0[w] = wsum; s1[w] = sy; s2[w] = sx; }
    __syncthreads();
    if (threadIdx.x == 0) {
        double W_ = s0[0] + s0[1] + s0[2] + s0[3];
        double SY = s1[0] + s1[1] + s1[2] + s1[3];
        double SX = s2[0] + s2[1] + s2[2] + s2[3];
        double tot = W_ + 1e-8;
        int x0 = (int)rint(SY / tot) - RAD;
        int y0 = (int)rint(SX / tot) - RAD;
        x0 = min(max(x0, 0), 512 - DSZ);
        y0 = min(max(y0, 0), 512 - DSZ);
        xy[jb * 2 + 0] = x0;
        xy[jb * 2 + 1] = y0;
    }
}

// one patch pass: crop->dot divide->grid_sample->write back (LDS stride PSTR)
__device__ __forceinline__ void patch_one(float* __restrict__ im, float* __restrict__ patch,
                                          int x0, int y0, float a,
                                          float t0, float t1, float t2,
                                          float t3, float t4, float t5) {
    for (int t = threadIdx.x; t < DSZ * DSZ; t += 1024) {
        int u = t / DSZ, v = t % DSZ;
        float val = im[(x0 + u) * 512 + (y0 + v)];
        int du = u - RAD, dv = v - RAD;
        if (du * du + dv * dv <= 16) val = val / a;
        patch[u * PSTR + v] = val;
    }
    __syncthreads();
    for (int t = threadIdx.x; t < DSZ * DSZ; t += 1024) {
        int py = t / DSZ, px = t % DSZ;
        float X = (2.0f * (float)px + 1.0f) / 120.0f - 1.0f;
        float Y = (2.0f * (float)py + 1.0f) / 120.0f - 1.0f;
        float gx = t0 * X + t1 * Y + t2;
        float gy = t3 * X + t4 * Y + t5;
        float o = gs_bilinear_patch(patch, gx, gy);
        im[(x0 + py) * 512 + (y0 + px)] = o;
    }
}

// stage 5: revise. One block per (b,j); parallel when rects disjoint,
// deterministic sequential fallback when any same-b rects overlap.
__global__ void __launch_bounds__(1024) k_patch(float* __restrict__ img,
                                                const int* __restrict__ xy,
                                                const float* __restrict__ inv1,
                                                const float* __restrict__ adj) {
    __shared__ float patch[DSZ * PSTR];
    int b = blockIdx.x >> 2, j = blockIdx.x & 3;
    int rx[4], ry[4];
    #pragma unroll
    for (int k = 0; k < 4; ++k) {
        rx[k] = xy[(k * 16 + b) * 2 + 0];
        ry[k] = xy[(k * 16 + b) * 2 + 1];
    }
    bool overlap = false;
    #pragma unroll
    for (int i = 0; i < 4; ++i)
        #pragma unroll
        for (int k = 0; k < 4; ++k)
            if (i < k && abs(rx[i] - rx[k]) < DSZ && abs(ry[i] - ry[k]) < DSZ)
                overlap = true;

    float a = adj[b];
    float* im = img + (size_t)b * NPIX;
    const float* th = inv1 + b * 6;
    float t0 = th[0], t1 = th[1], t2 = th[2], t3 = th[3], t4 = th[4], t5 = th[5];

    if (!overlap) {
        patch_one(im, patch, rx[j], ry[j], a, t0, t1, t2, t3, t4, t5);
    } else {
        if (j != 0) return;
        for (int jj = 0; jj < 4; ++jj) {
            patch_one(im, patch, rx[jj], ry[jj], a, t0, t1, t2, t3, t4, t5);
            __threadfence_block();
            __syncthreads();
        }
    }
}

// ---------------- launcher ----------------

extern "C" void kernel_launch(void* const* d_in, const int* in_sizes, int n_in,
                              void* d_out, int out_size, void* d_ws, size_t ws_size,
                              hipStream_t stream) {
    const float* base  = (const float*)d_in[0];
    const float* sc    = (const float*)d_in[1];
    const float* rot   = (const float*)d_in[2];
    const float* tr    = (const float*)d_in[3];
    const float* adj   = (const float*)d_in[4];
    const float* masks = (const float*)d_in[5];

    float* out  = (float*)d_out;
    float* out0 = out;                               // base_inp
    float* out1 = out0 + (size_t)NB * NPIX;          // pred_input
    float* out2 = out1 + (size_t)NB * NPIX;          // pred_revise
    float* out3 = out2 + (size_t)NB * NPIX;          // masks_rot (4,16,512,512)

    // ws layout (bytes): inv @0, xy @4096, bbox @8192, occ @12288,
    //                    qcount @16128, otile @16384 (64KB), queue @81920 (256KB)
    float*         inv1   = (float*)d_ws;
    float*         inv2   = inv1 + 96;
    float*         inv3   = inv1 + 192;
    int*           xy     = (int*)((char*)d_ws + 4096);
    int*           bbox   = (int*)((char*)d_ws + 8192);
    unsigned*      occ    = (unsigned*)((char*)d_ws + 12288);
    int*           qcount = (int*)((char*)d_ws + 16128);
    unsigned char* otile  = (unsigned char*)((char*)d_ws + 16384);
    int*           queue  = (int*)((char*)d_ws + 81920);

    // 1: occ + prep (small)
    k_pre<<<33, 256, 0, stream>>>(sc, rot, tr, masks, (float*)d_ws, bbox, occ, qcount);
    // 2: fused upsample + g3 + g2 + g1 (+ otile classification)
    k_main<<<4352, 256, 0, stream>>>(base, out0, out1, out2, inv1, inv2, inv3,
                                     occ, otile, queue, qcount);
    // 3: masked zero of dead tiles + mask chain on live tiles (disjoint writes)
    k_zml<<<3072, 256, 0, stream>>>(masks, out3, inv1, inv2, otile, queue, qcount, bbox);
    // 4: COM stats over per-(j,b) bounding boxes
    k_stats<<<64, 256, 0, stream>>>(out1, out3, bbox, xy);
    // 5: revise
    k_patch<<<64, 1024, 0, stream>>>(out2, xy, inv1, adj);
}